// Round 8
// baseline (102.314 us; speedup 1.0000x reference)
//
#include <hip/hip_runtime.h>
#include <hip/hip_bf16.h>

#define BB     64
#define NF4    200000        // NTOT / 4
#define CHUNKS 3125          // NF4 / 64
#define NP     128
#define NH1    256
#define NH2    128
#define NC     32
#define EPSV   1e-5f
#define NBLK   64            // blocks in fused head

typedef float fx4 __attribute__((ext_vector_type(4)));

#define AS_G __attribute__((address_space(1)))
#define AS_L __attribute__((address_space(3)))

__device__ __forceinline__ float dot4(fx4 a, fx4 b) {
    return fmaf(a[0], b[0], fmaf(a[1], b[1], fmaf(a[2], b[2], a[3] * b[3])));
}

// ---------------------------------------------------------------------------
// Scatter-reduce (UNCHANGED from R7: 89us total, proven). One wave/block,
// global_load_lds 8-slot ring, 7 loads in flight, premasked 2-pathway dot.
// ---------------------------------------------------------------------------
__global__ __launch_bounds__(64) void k_scatter(
    const float* __restrict__ x, const float* __restrict__ w,
    const int* __restrict__ idx, float* __restrict__ WX)
{
    __shared__ char lds[8 * 1024];       // 8 slots x 1KB
    const int lane = threadIdx.x;        // 0..63
    const int wid  = blockIdx.x;         // 0..6249
    const int ch   = wid >> 1;           // chunk id
    const int bh   = (wid & 1) << 5;     // batch-half start: 0 or 32
    const int n4   = ch * 64 + lane;

    const fx4*  __restrict__ w4 = reinterpret_cast<const fx4*>(w);
    const int4* __restrict__ p4 = reinterpret_cast<const int4*>(idx);
    const fx4*  __restrict__ x4 = reinterpret_cast<const fx4*>(x);

    const fx4  wv = w4[n4];
    const int4 pv = p4[n4];
    const int  pLo = __builtin_amdgcn_readfirstlane(pv.x);
    const int  pHi = __shfl(pv.w, 63);   // last element's pathway
    const bool uniform = (pLo == pHi);

    fx4 wLo, wHi;
    wLo[0] = (pv.x == pLo) ? wv[0] : 0.f;  wHi[0] = (pv.x == pHi) ? wv[0] : 0.f;
    wLo[1] = (pv.y == pLo) ? wv[1] : 0.f;  wHi[1] = (pv.y == pHi) ? wv[1] : 0.f;
    wLo[2] = (pv.z == pLo) ? wv[2] : 0.f;  wHi[2] = (pv.z == pHi) ? wv[2] : 0.f;
    wLo[3] = (pv.w == pLo) ? wv[3] : 0.f;  wHi[3] = (pv.w == pHi) ? wv[3] : 0.f;

    #pragma unroll
    for (int i = 0; i < 7; ++i) {
        const float* gp = (const float*)(x4 + ((size_t)(bh + i) * NF4 + n4));
        __builtin_amdgcn_global_load_lds((const AS_G float*)gp,
                                         (AS_L float*)(lds + i * 1024), 16, 0, 0);
    }

    #pragma unroll
    for (int i = 0; i < 32; ++i) {
        if (i < 25) {
            asm volatile("s_waitcnt vmcnt(6)" ::: "memory");
        } else if (i == 25) {
            asm volatile("s_waitcnt vmcnt(0)" ::: "memory");
        }
        __builtin_amdgcn_sched_barrier(0);

        const fx4 xr = *reinterpret_cast<const fx4*>(lds + (i & 7) * 1024 + lane * 16);
        float sLo = dot4(xr, wLo);
        if (uniform) {
            #pragma unroll
            for (int off = 1; off < 64; off <<= 1)
                sLo += __shfl_xor(sLo, off);
            if (lane == 0)
                atomicAdd(&WX[(bh + i) * NP + pLo], sLo);
        } else {
            float sHi = dot4(xr, wHi);
            #pragma unroll
            for (int off = 1; off < 64; off <<= 1) {
                sLo += __shfl_xor(sLo, off);
                sHi += __shfl_xor(sHi, off);
            }
            if (lane == 0) {
                atomicAdd(&WX[(bh + i) * NP + pLo], sLo);
                atomicAdd(&WX[(bh + i) * NP + pHi], sHi);
            }
        }
        __builtin_amdgcn_sched_barrier(0);

        if (i < 25) {
            const float* gp = (const float*)(x4 + ((size_t)(bh + i + 7) * NF4 + n4));
            __builtin_amdgcn_global_load_lds((const AS_G float*)gp,
                                             (AS_L float*)(lds + ((i + 7) & 7) * 1024),
                                             16, 0, 0);
        }
        __builtin_amdgcn_sched_barrier(0);
    }
}

// ---------------------------------------------------------------------------
// Zero WX + barrier counters (replaces hipMemsetAsync; PMC-visible).
// ---------------------------------------------------------------------------
__global__ void k_zero(float* __restrict__ WX, int* __restrict__ bar)
{
    const int i = blockIdx.x * 256 + threadIdx.x;
    if (i < BB * NP) WX[i] = 0.f;
    if (i < 8) bar[i] = 0;
}

// ---------------------------------------------------------------------------
// Fused head: BN0+gate -> fc1+ReLU+BN -> fc2+ReLU+BN -> logits+softmax.
// 64 blocks x 256 thr; 3 device-scope spin barriers (blocks trivially
// co-resident). Each stage writes activations TRANSPOSED [feat][batch] to
// ws (lane=batch -> coalesced), next stage LDS-loads them linearly.
// ---------------------------------------------------------------------------
__device__ __forceinline__ void gbar(int* c, int tid)
{
    __syncthreads();
    if (tid == 0) {
        __threadfence();
        atomicAdd(c, 1);
        while (__hip_atomic_load(c, __ATOMIC_ACQUIRE, __HIP_MEMORY_SCOPE_AGENT) < NBLK)
            __builtin_amdgcn_s_sleep(2);
    }
    __syncthreads();
    __threadfence();
}

__device__ __forceinline__ float bn_shfl(float a, float gj, float bj)
{
    float s = a, q = a * a;
    #pragma unroll
    for (int off = 32; off > 0; off >>= 1) {
        s += __shfl_xor(s, off);
        q += __shfl_xor(q, off);
    }
    const float m   = s * (1.f / BB);
    const float var = q * (1.f / BB) - m * m;
    return (a - m) * rsqrtf(var + EPSV) * gj + bj;
}

__global__ __launch_bounds__(256) void k_head_fused(
    const float* __restrict__ WX,   const float* __restrict__ co_w,
    const float* __restrict__ bn0g, const float* __restrict__ bn0b,
    const float* __restrict__ W1,   const float* __restrict__ b1,
    const float* __restrict__ bn1g, const float* __restrict__ bn1b,
    const float* __restrict__ W2,   const float* __restrict__ b2,
    const float* __restrict__ bn2g, const float* __restrict__ bn2b,
    const float* __restrict__ Wo,   const float* __restrict__ bo,
    float* __restrict__ y, float* __restrict__ Zout,
    float* __restrict__ Zt, float* __restrict__ h1t, float* __restrict__ h2t,
    int* __restrict__ bar)
{
    __shared__ float buf[16384];     // 64 KB, reused per stage
    const int tid  = threadIdx.x;
    const int wv   = tid >> 6;       // 0..3
    const int lane = tid & 63;       // == batch b
    const int blk  = blockIdx.x;     // 0..63

    // ---- stage 0: ReLU + BN0 + CancelOut. 2 pathways per block. ----
    if (wv < 2) {
        const int p = blk * 2 + wv;
        const float r = fmaxf(WX[lane * NP + p], 0.f);
        float s = r, q = r * r;
        #pragma unroll
        for (int off = 32; off > 0; off >>= 1) {
            s += __shfl_xor(s, off);
            q += __shfl_xor(q, off);
        }
        const float m   = s * (1.f / BB);
        const float var = q * (1.f / BB) - m * m;
        const float sig = 1.f / (1.f + expf(-co_w[p]));
        const float z = ((r - m) * rsqrtf(var + EPSV) * bn0g[p] + bn0b[p]) * sig;
        Zout[lane * NP + p] = z;        // required output (row-major)
        Zt[p * BB + lane]   = z;        // transposed copy: coalesced
    }
    gbar(&bar[0], tid);

    // ---- stage 1: fc1 + ReLU + BN. j = blk*4 + wv. ----
    #pragma unroll
    for (int r = 0; r < 8; ++r) {     // load Zt (8192 f) linearly into LDS
        const int f4 = tid + 256 * r;
        reinterpret_cast<fx4*>(buf)[f4] = reinterpret_cast<const fx4*>(Zt)[f4];
    }
    __syncthreads();
    {
        const int j = blk * 4 + wv;
        float acc = b1[j];
        #pragma unroll 8
        for (int k = 0; k < NP; ++k)
            acc = fmaf(buf[k * BB + lane], W1[k * NH1 + j], acc);
        h1t[j * BB + lane] = bn_shfl(fmaxf(acc, 0.f), bn1g[j], bn1b[j]);
    }
    gbar(&bar[1], tid);

    // ---- stage 2: fc2 + ReLU + BN. j = blk*2 + wv (waves 0,1). ----
    #pragma unroll
    for (int r = 0; r < 16; ++r) {    // load h1t (16384 f) linearly into LDS
        const int f4 = tid + 256 * r;
        reinterpret_cast<fx4*>(buf)[f4] = reinterpret_cast<const fx4*>(h1t)[f4];
    }
    __syncthreads();
    if (wv < 2) {
        const int j = blk * 2 + wv;
        float acc = b2[j];
        #pragma unroll 8
        for (int k = 0; k < NH1; ++k)
            acc = fmaf(buf[k * BB + lane], W2[k * NH2 + j], acc);
        h2t[j * BB + lane] = bn_shfl(fmaxf(acc, 0.f), bn2g[j], bn2b[j]);
    }
    gbar(&bar[2], tid);

    // ---- stage 3: logits + softmax. Row b = blk, wave 0 only. ----
    if (wv == 0) {
        const int b  = blk;
        const int c  = lane & 31;
        const int kh = lane >> 5;
        float acc = 0.f;
        #pragma unroll 8
        for (int k = kh * 64; k < kh * 64 + 64; ++k)
            acc = fmaf(h2t[k * BB + b], Wo[k * NC + c], acc);
        acc += __shfl_xor(acc, 32);
        acc += bo[c];
        float mx = acc;
        #pragma unroll
        for (int off = 16; off > 0; off >>= 1)
            mx = fmaxf(mx, __shfl_xor(mx, off));
        const float e = expf(acc - mx);
        float sm = e;
        #pragma unroll
        for (int off = 16; off > 0; off >>= 1)
            sm += __shfl_xor(sm, off);
        if (lane < 32)
            y[b * NC + c] = e / sm;
    }
}

// ---------------------------------------------------------------------------
extern "C" void kernel_launch(void* const* d_in, const int* in_sizes, int n_in,
                              void* d_out, int out_size, void* d_ws, size_t ws_size,
                              hipStream_t stream)
{
    const float* x    = (const float*)d_in[0];
    const float* w    = (const float*)d_in[1];
    const float* co_w = (const float*)d_in[2];
    const float* bn0g = (const float*)d_in[3];
    const float* bn0b = (const float*)d_in[4];
    const float* W1   = (const float*)d_in[5];
    const float* b1   = (const float*)d_in[6];
    const float* bn1g = (const float*)d_in[7];
    const float* bn1b = (const float*)d_in[8];
    const float* W2   = (const float*)d_in[9];
    const float* b2   = (const float*)d_in[10];
    const float* bn2g = (const float*)d_in[11];
    const float* bn2b = (const float*)d_in[12];
    const float* Wo   = (const float*)d_in[13];
    const float* bo   = (const float*)d_in[14];
    const int*   idx  = (const int*)d_in[15];

    float* out = (float*)d_out;
    float* y   = out;               // [64, 32]  (output 0)
    float* Z   = out + BB * NC;     // [64, 128] (output 1)

    float* WX  = (float*)d_ws;          // 8192 f32
    float* Zt  = WX  + BB * NP;         // 8192 f32   [p][b]
    float* h1t = Zt  + BB * NP;         // 16384 f32  [j][b]
    float* h2t = h1t + BB * NH1;        // 8192 f32   [j][b]
    int*   bar = (int*)(h2t + BB * NH2);

    k_zero<<<32, 256, 0, stream>>>(WX, bar);
    k_scatter<<<CHUNKS * 2, 64, 0, stream>>>(x, w, idx, WX);
    k_head_fused<<<NBLK, 256, 0, stream>>>(WX, co_w, bn0g, bn0b,
                                           W1, b1, bn1g, bn1b,
                                           W2, b2, bn2g, bn2b,
                                           Wo, bo, y, Z, Zt, h1t, h2t, bar);
}

// Round 9
// 91.849 us; speedup vs baseline: 1.1139x; 1.1139x over previous
//
#include <hip/hip_runtime.h>
#include <hip/hip_bf16.h>

#define BB     64
#define NF4    200000        // NTOT / 4
#define CHUNKS 3125          // NF4 / 64
#define NP     128
#define NH1    256
#define NH2    128
#define NC     32
#define EPSV   1e-5f

typedef float fx4 __attribute__((ext_vector_type(4)));

#define AS_G __attribute__((address_space(1)))
#define AS_L __attribute__((address_space(3)))

__device__ __forceinline__ float dot4(fx4 a, fx4 b) {
    return fmaf(a[0], b[0], fmaf(a[1], b[1], fmaf(a[2], b[2], a[3] * b[3])));
}

// ---------------------------------------------------------------------------
// Scatter-reduce: WX[b, idx[n]] += x[b,n] * w[n]     (idx sorted)
// One wave per block, global_load_lds 8-slot/1KB ring. CHANGE vs R7: the
// LDS consume is an inline-asm ds_read_b128 (+fused lgkmcnt(0)), so the
// compiler's waitcnt pass never sees an LDS load aliasing the DMA dest and
// cannot insert its serializing vmcnt(0). Refill issued at iteration TOP
// (slot freed last iter) -> load in flight across the whole shuffle chain.
// ---------------------------------------------------------------------------
__global__ __launch_bounds__(64) void k_scatter(
    const float* __restrict__ x, const float* __restrict__ w,
    const int* __restrict__ idx, float* __restrict__ WX)
{
    __shared__ char lds[8 * 1024];       // 8 slots x 1KB
    const int lane = threadIdx.x;        // 0..63
    const int wid  = blockIdx.x;         // 0..6249
    const int ch   = wid >> 1;           // chunk id
    const int bh   = (wid & 1) << 5;     // batch-half start: 0 or 32
    const int n4   = ch * 64 + lane;

    const fx4*  __restrict__ w4 = reinterpret_cast<const fx4*>(w);
    const int4* __restrict__ p4 = reinterpret_cast<const int4*>(idx);
    const fx4*  __restrict__ x4 = reinterpret_cast<const fx4*>(x);

    const fx4  wv = w4[n4];
    const int4 pv = p4[n4];
    const int  pLo = __builtin_amdgcn_readfirstlane(pv.x);
    const int  pHi = __shfl(pv.w, 63);   // last element's pathway
    const bool uniform = (pLo == pHi);

    fx4 wLo, wHi;
    wLo[0] = (pv.x == pLo) ? wv[0] : 0.f;  wHi[0] = (pv.x == pHi) ? wv[0] : 0.f;
    wLo[1] = (pv.y == pLo) ? wv[1] : 0.f;  wHi[1] = (pv.y == pHi) ? wv[1] : 0.f;
    wLo[2] = (pv.z == pLo) ? wv[2] : 0.f;  wHi[2] = (pv.z == pHi) ? wv[2] : 0.f;
    wLo[3] = (pv.w == pLo) ? wv[3] : 0.f;  wHi[3] = (pv.w == pHi) ? wv[3] : 0.f;

    auto stage = [&](int bi) {
        const float* gp = (const float*)(x4 + ((size_t)(bh + bi) * NF4 + n4));
        __builtin_amdgcn_global_load_lds((const AS_G float*)gp,
                                         (AS_L float*)(lds + (bi & 7) * 1024),
                                         16, 0, 0);
    };

    #pragma unroll
    for (int i = 0; i < 7; ++i) stage(i);     // slots 0..6 in flight

    #pragma unroll
    for (int i = 0; i < 32; ++i) {
        if (i < 25) {
            stage(i + 7);                     // slot (i-1)&7, freed last iter
            asm volatile("s_waitcnt vmcnt(6)" ::: "memory");   // slot i&7 landed
        } else if (i == 25) {
            asm volatile("s_waitcnt vmcnt(0)" ::: "memory");   // tail drain
        }

        // Consume via asm: invisible to compiler's conservative waitcnt pass.
        const unsigned laddr =
            (unsigned)(size_t)(AS_L char*)(lds + (i & 7) * 1024 + lane * 16);
        fx4 xr;
        asm volatile("ds_read_b128 %0, %1\n\ts_waitcnt lgkmcnt(0)"
                     : "=v"(xr) : "v"(laddr));

        float sLo = dot4(xr, wLo);
        if (uniform) {
            #pragma unroll
            for (int off = 1; off < 64; off <<= 1)
                sLo += __shfl_xor(sLo, off);
            if (lane == 0)
                atomicAdd(&WX[(bh + i) * NP + pLo], sLo);
        } else {
            float sHi = dot4(xr, wHi);
            #pragma unroll
            for (int off = 1; off < 64; off <<= 1) {
                sLo += __shfl_xor(sLo, off);
                sHi += __shfl_xor(sHi, off);
            }
            if (lane == 0) {
                atomicAdd(&WX[(bh + i) * NP + pLo], sLo);
                atomicAdd(&WX[(bh + i) * NP + pHi], sHi);
            }
        }
    }
}

// ---------------------------------------------------------------------------
// Zero WX (replaces hipMemsetAsync; PMC-visible).
// ---------------------------------------------------------------------------
__global__ void k_zero(float* __restrict__ WX)
{
    const int i = blockIdx.x * 256 + threadIdx.x;
    if (i < BB * NP) WX[i] = 0.f;
}

__device__ __forceinline__ float bn_shfl(float a, float gj, float bj)
{
    float s = a, q = a * a;
    #pragma unroll
    for (int off = 32; off > 0; off >>= 1) {
        s += __shfl_xor(s, off);
        q += __shfl_xor(q, off);
    }
    const float m   = s * (1.f / BB);
    const float var = q * (1.f / BB) - m * m;
    return (a - m) * rsqrtf(var + EPSV) * gj + bj;
}

// ---------------------------------------------------------------------------
// BN0+gate (redundant per block, parallel) + fc1 + ReLU + BN1.
// 64 blocks x 256 thr; block computes Z into padded LDS (conflict-free),
// then its 4 waves produce h1 columns j=blk*4+wv (transposed [j][b]).
// Block 0 also writes the required Z output (row-major).
// ---------------------------------------------------------------------------
__global__ __launch_bounds__(256) void k_fc1z(
    const float* __restrict__ WX,   const float* __restrict__ co_w,
    const float* __restrict__ bn0g, const float* __restrict__ bn0b,
    const float* __restrict__ W1,   const float* __restrict__ b1,
    const float* __restrict__ bn1g, const float* __restrict__ bn1b,
    float* __restrict__ Zout, float* __restrict__ h1t)
{
    __shared__ float Zl[NP * 65];    // pad 65: conflict-free write & read
    const int tid  = threadIdx.x;
    const int wv   = tid >> 6;
    const int lane = tid & 63;       // == batch in fc1 stage
    const int blk  = blockIdx.x;

    if (tid < NP) {
        const int p = tid;           // pathway; WX reads coalesced across p
        float sum = 0.f, sq = 0.f;
        #pragma unroll 8
        for (int b = 0; b < BB; ++b) {
            const float r = fmaxf(WX[b * NP + p], 0.f);
            sum += r; sq += r * r;
        }
        const float m   = sum * (1.f / BB);
        const float var = sq * (1.f / BB) - m * m;
        const float sc  = rsqrtf(var + EPSV) * bn0g[p];
        const float bt  = bn0b[p];
        const float sig = 1.f / (1.f + expf(-co_w[p]));
        #pragma unroll 8
        for (int b = 0; b < BB; ++b) {
            const float r = fmaxf(WX[b * NP + p], 0.f);
            const float z = ((r - m) * sc + bt) * sig;
            Zl[p * 65 + b] = z;
            if (blk == 0) Zout[b * NP + p] = z;   // coalesced across p
        }
    }
    __syncthreads();

    const int j = blk * 4 + wv;      // 0..255
    float acc = b1[j];
    #pragma unroll 8
    for (int k = 0; k < NP; ++k)
        acc = fmaf(Zl[k * 65 + lane], W1[k * NH1 + j], acc);
    h1t[j * BB + lane] = bn_shfl(fmaxf(acc, 0.f), bn1g[j], bn1b[j]);
}

// ---------------------------------------------------------------------------
// fc2 + ReLU + BN2 from TRANSPOSED input [K][BB]. One block per column j,
// 64 threads = batch. in_t reads are coalesced (lane=b consecutive).
// ---------------------------------------------------------------------------
template <int K, int NOUT>
__global__ void k_fc_bn_t(const float* __restrict__ in_t,  // [K][BB]
                          const float* __restrict__ W,     // [K, NOUT]
                          const float* __restrict__ bias,
                          const float* __restrict__ g,
                          const float* __restrict__ beta,
                          float* __restrict__ out_t)       // [NOUT][BB]
{
    const int j = blockIdx.x;
    const int b = threadIdx.x;  // 0..63
    float acc = bias[j];
    #pragma unroll 8
    for (int k = 0; k < K; ++k)
        acc = fmaf(in_t[k * BB + b], W[k * NOUT + j], acc);
    out_t[j * BB + b] = bn_shfl(fmaxf(acc, 0.f), g[j], beta[j]);
}

// ---------------------------------------------------------------------------
// Final Linear + row softmax from transposed h2 [NH2][BB].
// One block per batch row, 32 threads = classes; h2 reads are broadcast.
// ---------------------------------------------------------------------------
__global__ void k_head(const float* __restrict__ h2t,  // [NH2][BB]
                       const float* __restrict__ Wo,   // [NH2, NC]
                       const float* __restrict__ bo,
                       float* __restrict__ y)          // [BB, NC]
{
    const int b = blockIdx.x;
    const int c = threadIdx.x;  // 0..31
    float acc = bo[c];
    #pragma unroll 8
    for (int k = 0; k < NH2; ++k)
        acc = fmaf(h2t[k * BB + b], Wo[k * NC + c], acc);
    float mx = acc;
    #pragma unroll
    for (int off = 16; off > 0; off >>= 1)
        mx = fmaxf(mx, __shfl_xor(mx, off));
    const float e = expf(acc - mx);
    float s = e;
    #pragma unroll
    for (int off = 16; off > 0; off >>= 1)
        s += __shfl_xor(s, off);
    y[b * NC + c] = e / s;
}

// ---------------------------------------------------------------------------
extern "C" void kernel_launch(void* const* d_in, const int* in_sizes, int n_in,
                              void* d_out, int out_size, void* d_ws, size_t ws_size,
                              hipStream_t stream)
{
    const float* x    = (const float*)d_in[0];
    const float* w    = (const float*)d_in[1];
    const float* co_w = (const float*)d_in[2];
    const float* bn0g = (const float*)d_in[3];
    const float* bn0b = (const float*)d_in[4];
    const float* W1   = (const float*)d_in[5];
    const float* b1   = (const float*)d_in[6];
    const float* bn1g = (const float*)d_in[7];
    const float* bn1b = (const float*)d_in[8];
    const float* W2   = (const float*)d_in[9];
    const float* b2   = (const float*)d_in[10];
    const float* bn2g = (const float*)d_in[11];
    const float* bn2b = (const float*)d_in[12];
    const float* Wo   = (const float*)d_in[13];
    const float* bo   = (const float*)d_in[14];
    const int*   idx  = (const int*)d_in[15];

    float* out = (float*)d_out;
    float* y   = out;               // [64, 32]  (output 0)
    float* Z   = out + BB * NC;     // [64, 128] (output 1)

    float* WX  = (float*)d_ws;          // 8192 f32
    float* h1t = WX + BB * NP;          // 16384 f32  [j][b]
    float* h2t = h1t + BB * NH1;        // 8192 f32   [j][b]

    k_zero<<<32, 256, 0, stream>>>(WX);
    k_scatter<<<CHUNKS * 2, 64, 0, stream>>>(x, w, idx, WX);
    k_fc1z<<<64, 256, 0, stream>>>(WX, co_w, bn0g, bn0b,
                                   W1, b1, bn1g, bn1b, Z, h1t);
    k_fc_bn_t<NH1, NH2><<<NH2, BB, 0, stream>>>(h1t, W2, b2, bn2g, bn2b, h2t);
    k_head<<<BB, NC, 0, stream>>>(h2t, Wo, bo, y);
}

// Round 10
// 87.509 us; speedup vs baseline: 1.1692x; 1.0496x over previous
//
#include <hip/hip_runtime.h>
#include <hip/hip_bf16.h>
#include <type_traits>

#define BB     64
#define NF4    200000        // NTOT / 4
#define CHUNKS 3125          // NF4 / 64
#define NP     128
#define NH1    256
#define NH2    128
#define NC     32
#define EPSV   1e-5f

typedef float fx4 __attribute__((ext_vector_type(4)));

#define AS_G __attribute__((address_space(1)))
#define AS_L __attribute__((address_space(3)))

__device__ __forceinline__ float dot4(fx4 a, fx4 b) {
    return fmaf(a[0], b[0], fmaf(a[1], b[1], fmaf(a[2], b[2], a[3] * b[3])));
}

template <int N, int I = 0, typename F>
__device__ __forceinline__ void static_for(F&& f) {
    if constexpr (I < N) {
        f(std::integral_constant<int, I>{});
        static_for<N, I + 1>(f);
    }
}

__device__ __forceinline__ int bitrev5(int l) {
    return ((l & 1) << 4) | ((l & 2) << 2) | (l & 4) | ((l & 8) >> 2) | ((l & 16) >> 4);
}

template <int C, int M>
__device__ __forceinline__ void red_step(float* v, int lane) {
    const bool hi = (lane & M) != 0;
    #pragma unroll
    for (int j = 0; j < C / 2; ++j) {
        float mine  = hi ? v[j + C / 2] : v[j];
        float other = hi ? v[j]         : v[j + C / 2];
        v[j] = mine + __shfl_xor(other, M);
    }
}

// Reduce acc[32] (each lane: partials for 32 batches) -> 32 batch sums,
// one per lane (batch bitrev5(lane) at lanes 0..31), then ONE atomic instr.
__device__ __forceinline__ void reduce_emit(float* acc, int lane, int bh,
                                            int path, float* __restrict__ WX) {
    red_step<32, 1>(acc, lane);
    red_step<16, 2>(acc, lane);
    red_step<8,  4>(acc, lane);
    red_step<4,  8>(acc, lane);
    red_step<2, 16>(acc, lane);
    float s = acc[0];
    s += __shfl_xor(s, 32);
    if (lane < 32)
        atomicAdd(&WX[(bh + bitrev5(lane)) * NP + path], s);
}

// ---------------------------------------------------------------------------
// Scatter-reduce: WX[b, idx[n]] += x[b,n] * w[n]     (idx sorted)
// One wave per block; wave owns one 64-quad chunk x 32 batch rows.
// NEW vs R9: stage ALL 32 rows (32KB LDS) via global_load_lds, ONE
// vmcnt(0) drain, then pure LDS/VALU: 32 independent ds_read+dot into an
// unrolled acc[32], one 32-shuffle transpose-reduce, ONE atomic per wave.
// The vmcnt queue contains ONLY loads (atomics no longer poison it).
// ---------------------------------------------------------------------------
__global__ __launch_bounds__(64) void k_scatter(
    const float* __restrict__ x, const float* __restrict__ w,
    const int* __restrict__ idx, float* __restrict__ WX)
{
    __shared__ fx4 lds4[32 * 64];        // 32 rows x 1KB
    const int lane = threadIdx.x;        // 0..63
    const int wid  = blockIdx.x;         // 0..6249
    const int ch   = wid >> 1;           // chunk id
    const int bh   = (wid & 1) << 5;     // batch-half start: 0 or 32
    const int n4   = ch * 64 + lane;

    const fx4*  __restrict__ w4 = reinterpret_cast<const fx4*>(w);
    const int4* __restrict__ p4 = reinterpret_cast<const int4*>(idx);
    const fx4*  __restrict__ x4 = reinterpret_cast<const fx4*>(x);

    const fx4  wv = w4[n4];
    const int4 pv = p4[n4];
    const int  pLo = __builtin_amdgcn_readfirstlane(pv.x);
    const int  pHi = __shfl(pv.w, 63);   // last element's pathway
    const bool uniform = (pLo == pHi);

    // Premasked weights (wLo == wv when uniform).
    fx4 wLo, wHi;
    wLo[0] = (pv.x == pLo) ? wv[0] : 0.f;  wHi[0] = (pv.x == pHi) ? wv[0] : 0.f;
    wLo[1] = (pv.y == pLo) ? wv[1] : 0.f;  wHi[1] = (pv.y == pHi) ? wv[1] : 0.f;
    wLo[2] = (pv.z == pLo) ? wv[2] : 0.f;  wHi[2] = (pv.z == pHi) ? wv[2] : 0.f;
    wLo[3] = (pv.w == pLo) ? wv[3] : 0.f;  wHi[3] = (pv.w == pHi) ? wv[3] : 0.f;

    // Stage the whole 32-row tile: 32 outstanding 1KB DMA loads.
    static_for<32>([&](auto I) {
        constexpr int i = I.value;
        const float* gp = (const float*)(x4 + ((size_t)(bh + i) * NF4 + n4));
        __builtin_amdgcn_global_load_lds((const AS_G float*)gp,
                                         (AS_L float*)(lds4 + i * 64), 16, 0, 0);
    });
    asm volatile("s_waitcnt vmcnt(0)" ::: "memory");   // single drain

    if (uniform) {
        float acc[32];
        static_for<32>([&](auto I) {
            constexpr int i = I.value;
            acc[i] = dot4(lds4[i * 64 + lane], wLo);
        });
        reduce_emit(acc, lane, bh, pLo, WX);
    } else {                                  // pathway boundary chunk (~4%)
        float acc[32], accH[32];
        static_for<32>([&](auto I) {
            constexpr int i = I.value;
            const fx4 xr = lds4[i * 64 + lane];
            acc[i]  = dot4(xr, wLo);
            accH[i] = dot4(xr, wHi);
        });
        reduce_emit(acc,  lane, bh, pLo, WX);
        reduce_emit(accH, lane, bh, pHi, WX);
    }
}

// ---------------------------------------------------------------------------
// Zero WX (replaces hipMemsetAsync; PMC-visible).
// ---------------------------------------------------------------------------
__global__ void k_zero(float* __restrict__ WX)
{
    const int i = blockIdx.x * 256 + threadIdx.x;
    if (i < BB * NP) WX[i] = 0.f;
}

__device__ __forceinline__ float bn_shfl(float a, float gj, float bj)
{
    float s = a, q = a * a;
    #pragma unroll
    for (int off = 32; off > 0; off >>= 1) {
        s += __shfl_xor(s, off);
        q += __shfl_xor(q, off);
    }
    const float m   = s * (1.f / BB);
    const float var = q * (1.f / BB) - m * m;
    return (a - m) * rsqrtf(var + EPSV) * gj + bj;
}

// ---------------------------------------------------------------------------
// BN0+gate (redundant per block, parallel) + fc1 + ReLU + BN1.
// 64 blocks x 256 thr; block computes Z into padded LDS (conflict-free),
// then its 4 waves produce h1 columns j=blk*4+wv (transposed [j][b]).
// Block 0 also writes the required Z output (row-major).
// ---------------------------------------------------------------------------
__global__ __launch_bounds__(256) void k_fc1z(
    const float* __restrict__ WX,   const float* __restrict__ co_w,
    const float* __restrict__ bn0g, const float* __restrict__ bn0b,
    const float* __restrict__ W1,   const float* __restrict__ b1,
    const float* __restrict__ bn1g, const float* __restrict__ bn1b,
    float* __restrict__ Zout, float* __restrict__ h1t)
{
    __shared__ float Zl[NP * 65];    // pad 65: conflict-free write & read
    const int tid  = threadIdx.x;
    const int wv   = tid >> 6;
    const int lane = tid & 63;       // == batch in fc1 stage
    const int blk  = blockIdx.x;

    if (tid < NP) {
        const int p = tid;
        float sum = 0.f, sq = 0.f;
        #pragma unroll 8
        for (int b = 0; b < BB; ++b) {
            const float r = fmaxf(WX[b * NP + p], 0.f);
            sum += r; sq += r * r;
        }
        const float m   = sum * (1.f / BB);
        const float var = sq * (1.f / BB) - m * m;
        const float sc  = rsqrtf(var + EPSV) * bn0g[p];
        const float bt  = bn0b[p];
        const float sig = 1.f / (1.f + expf(-co_w[p]));
        #pragma unroll 8
        for (int b = 0; b < BB; ++b) {
            const float r = fmaxf(WX[b * NP + p], 0.f);
            const float z = ((r - m) * sc + bt) * sig;
            Zl[p * 65 + b] = z;
            if (blk == 0) Zout[b * NP + p] = z;
        }
    }
    __syncthreads();

    const int j = blk * 4 + wv;      // 0..255
    float acc = b1[j];
    #pragma unroll 8
    for (int k = 0; k < NP; ++k)
        acc = fmaf(Zl[k * 65 + lane], W1[k * NH1 + j], acc);
    h1t[j * BB + lane] = bn_shfl(fmaxf(acc, 0.f), bn1g[j], bn1b[j]);
}

// ---------------------------------------------------------------------------
// fc2 + ReLU + BN2 from TRANSPOSED input [K][BB]. One block per column j.
// ---------------------------------------------------------------------------
template <int K, int NOUT>
__global__ void k_fc_bn_t(const float* __restrict__ in_t,  // [K][BB]
                          const float* __restrict__ W,     // [K, NOUT]
                          const float* __restrict__ bias,
                          const float* __restrict__ g,
                          const float* __restrict__ beta,
                          float* __restrict__ out_t)       // [NOUT][BB]
{
    const int j = blockIdx.x;
    const int b = threadIdx.x;  // 0..63
    float acc = bias[j];
    #pragma unroll 8
    for (int k = 0; k < K; ++k)
        acc = fmaf(in_t[k * BB + b], W[k * NOUT + j], acc);
    out_t[j * BB + b] = bn_shfl(fmaxf(acc, 0.f), g[j], beta[j]);
}

// ---------------------------------------------------------------------------
// Final Linear + row softmax from transposed h2 [NH2][BB].
// ---------------------------------------------------------------------------
__global__ void k_head(const float* __restrict__ h2t,  // [NH2][BB]
                       const float* __restrict__ Wo,   // [NH2, NC]
                       const float* __restrict__ bo,
                       float* __restrict__ y)          // [BB, NC]
{
    const int b = blockIdx.x;
    const int c = threadIdx.x;  // 0..31
    float acc = bo[c];
    #pragma unroll 8
    for (int k = 0; k < NH2; ++k)
        acc = fmaf(h2t[k * BB + b], Wo[k * NC + c], acc);
    float mx = acc;
    #pragma unroll
    for (int off = 16; off > 0; off >>= 1)
        mx = fmaxf(mx, __shfl_xor(mx, off));
    const float e = expf(acc - mx);
    float s = e;
    #pragma unroll
    for (int off = 16; off > 0; off >>= 1)
        s += __shfl_xor(s, off);
    y[b * NC + c] = e / s;
}

// ---------------------------------------------------------------------------
extern "C" void kernel_launch(void* const* d_in, const int* in_sizes, int n_in,
                              void* d_out, int out_size, void* d_ws, size_t ws_size,
                              hipStream_t stream)
{
    const float* x    = (const float*)d_in[0];
    const float* w    = (const float*)d_in[1];
    const float* co_w = (const float*)d_in[2];
    const float* bn0g = (const float*)d_in[3];
    const float* bn0b = (const float*)d_in[4];
    const float* W1   = (const float*)d_in[5];
    const float* b1   = (const float*)d_in[6];
    const float* bn1g = (const float*)d_in[7];
    const float* bn1b = (const float*)d_in[8];
    const float* W2   = (const float*)d_in[9];
    const float* b2   = (const float*)d_in[10];
    const float* bn2g = (const float*)d_in[11];
    const float* bn2b = (const float*)d_in[12];
    const float* Wo   = (const float*)d_in[13];
    const float* bo   = (const float*)d_in[14];
    const int*   idx  = (const int*)d_in[15];

    float* out = (float*)d_out;
    float* y   = out;               // [64, 32]  (output 0)
    float* Z   = out + BB * NC;     // [64, 128] (output 1)

    float* WX  = (float*)d_ws;          // 8192 f32
    float* h1t = WX + BB * NP;          // 16384 f32  [j][b]
    float* h2t = h1t + BB * NH1;        // 8192 f32   [j][b]

    k_zero<<<32, 256, 0, stream>>>(WX);
    k_scatter<<<CHUNKS * 2, 64, 0, stream>>>(x, w, idx, WX);
    k_fc1z<<<64, 256, 0, stream>>>(WX, co_w, bn0g, bn0b,
                                   W1, b1, bn1g, bn1b, Z, h1t);
    k_fc_bn_t<NH1, NH2><<<NH2, BB, 0, stream>>>(h1t, W2, b2, bn2g, bn2b, h2t);
    k_head<<<BB, NC, 0, stream>>>(h2t, Wo, bo, y);
}

// Round 11
// 84.231 us; speedup vs baseline: 1.2147x; 1.0389x over previous
//
#include <hip/hip_runtime.h>
#include <hip/hip_bf16.h>
#include <type_traits>

#define BB     64
#define NF4    200000        // NTOT / 4
#define CHUNKS 3125          // NF4 / 64
#define NP     128
#define NH1    256
#define NH2    128
#define NC     32
#define EPSV   1e-5f

typedef float fx4 __attribute__((ext_vector_type(4)));

#define AS_G __attribute__((address_space(1)))
#define AS_L __attribute__((address_space(3)))

__device__ __forceinline__ float dot4(fx4 a, fx4 b) {
    return fmaf(a[0], b[0], fmaf(a[1], b[1], fmaf(a[2], b[2], a[3] * b[3])));
}

template <int N, int I = 0, typename F>
__device__ __forceinline__ void static_for(F&& f) {
    if constexpr (I < N) {
        f(std::integral_constant<int, I>{});
        static_for<N, I + 1>(f);
    }
}

__device__ __forceinline__ int bitrev3(int l) {
    return ((l & 1) << 2) | (l & 2) | ((l & 4) >> 2);
}

template <int C, int M>
__device__ __forceinline__ void red_step(float* v, int lane) {
    const bool hi = (lane & M) != 0;
    #pragma unroll
    for (int j = 0; j < C / 2; ++j) {
        float mine  = hi ? v[j + C / 2] : v[j];
        float other = hi ? v[j]         : v[j + C / 2];
        v[j] = mine + __shfl_xor(other, M);
    }
}

// Reduce acc[8] (each lane: partials for 8 batches) -> full sums; lanes 0..7
// hold batch b0+bitrev3(lane); ONE atomic instruction per wave.
__device__ __forceinline__ void reduce_emit8(float* acc, int lane, int b0,
                                             int path, float* __restrict__ WX) {
    red_step<8, 1>(acc, lane);
    red_step<4, 2>(acc, lane);
    red_step<2, 4>(acc, lane);
    float s = acc[0];
    s += __shfl_xor(s, 8);
    s += __shfl_xor(s, 16);
    s += __shfl_xor(s, 32);
    if (lane < 8)
        atomicAdd(&WX[(b0 + bitrev3(lane)) * NP + path], s);
}

// ---------------------------------------------------------------------------
// Scatter-reduce: WX[b, idx[n]] += x[b,n] * w[n]     (idx sorted)
// 256-thread blocks, 4 waves. Block owns (chunk, batch-half); each wave
// independently stages ITS 8 rows (8KB) via global_load_lds into its own
// LDS quarter, drains its own vmcnt, dots, 10-shuffle reduce, 8-lane
// atomic. Same 32KB/block (5 blocks/CU) but 20 waves/CU (was 5): staging,
// compute, and retire phases of different waves now overlap.
// ---------------------------------------------------------------------------
__global__ __launch_bounds__(256) void k_scatter(
    const float* __restrict__ x, const float* __restrict__ w,
    const int* __restrict__ idx, float* __restrict__ WX)
{
    __shared__ fx4 lds4[32 * 64];        // 4 waves x 8 rows x 1KB
    const int tid  = threadIdx.x;
    const int lane = tid & 63;
    const int wq   = tid >> 6;           // wave 0..3
    const int wid  = blockIdx.x;         // 0..6249
    const int ch   = wid >> 1;           // chunk id
    const int b0   = ((wid & 1) << 5) + wq * 8;   // this wave's batch start
    const int n4   = ch * 64 + lane;

    const fx4*  __restrict__ w4 = reinterpret_cast<const fx4*>(w);
    const int4* __restrict__ p4 = reinterpret_cast<const int4*>(idx);
    const fx4*  __restrict__ x4 = reinterpret_cast<const fx4*>(x);

    const fx4  wv = w4[n4];
    const int4 pv = p4[n4];
    const int  pLo = __builtin_amdgcn_readfirstlane(pv.x);
    const int  pHi = __shfl(pv.w, 63);   // last element's pathway
    const bool uniform = (pLo == pHi);

    fx4 wLo, wHi;
    wLo[0] = (pv.x == pLo) ? wv[0] : 0.f;  wHi[0] = (pv.x == pHi) ? wv[0] : 0.f;
    wLo[1] = (pv.y == pLo) ? wv[1] : 0.f;  wHi[1] = (pv.y == pHi) ? wv[1] : 0.f;
    wLo[2] = (pv.z == pLo) ? wv[2] : 0.f;  wHi[2] = (pv.z == pHi) ? wv[2] : 0.f;
    wLo[3] = (pv.w == pLo) ? wv[3] : 0.f;  wHi[3] = (pv.w == pHi) ? wv[3] : 0.f;

    fx4* const myl = lds4 + wq * 8 * 64;  // wave-private LDS slice

    // Stage this wave's 8 rows: 8 outstanding 1KB DMA loads.
    static_for<8>([&](auto I) {
        constexpr int i = I.value;
        const float* gp = (const float*)(x4 + ((size_t)(b0 + i) * NF4 + n4));
        __builtin_amdgcn_global_load_lds((const AS_G float*)gp,
                                         (AS_L float*)(myl + i * 64), 16, 0, 0);
    });
    asm volatile("s_waitcnt vmcnt(0)" ::: "memory");   // own loads only

    if (uniform) {
        float acc[8];
        static_for<8>([&](auto I) {
            constexpr int i = I.value;
            acc[i] = dot4(myl[i * 64 + lane], wLo);
        });
        reduce_emit8(acc, lane, b0, pLo, WX);
    } else {                                  // pathway-boundary chunk (~4%)
        float acc[8], accH[8];
        static_for<8>([&](auto I) {
            constexpr int i = I.value;
            const fx4 xr = myl[i * 64 + lane];
            acc[i]  = dot4(xr, wLo);
            accH[i] = dot4(xr, wHi);
        });
        reduce_emit8(acc,  lane, b0, pLo, WX);
        reduce_emit8(accH, lane, b0, pHi, WX);
    }
}

// ---------------------------------------------------------------------------
// Zero WX (replaces hipMemsetAsync; PMC-visible).
// ---------------------------------------------------------------------------
__global__ void k_zero(float* __restrict__ WX)
{
    const int i = blockIdx.x * 256 + threadIdx.x;
    if (i < BB * NP) WX[i] = 0.f;
}

__device__ __forceinline__ float bn_shfl(float a, float gj, float bj)
{
    float s = a, q = a * a;
    #pragma unroll
    for (int off = 32; off > 0; off >>= 1) {
        s += __shfl_xor(s, off);
        q += __shfl_xor(q, off);
    }
    const float m   = s * (1.f / BB);
    const float var = q * (1.f / BB) - m * m;
    return (a - m) * rsqrtf(var + EPSV) * gj + bj;
}

// ---------------------------------------------------------------------------
// BN0+gate (redundant per block, parallel) + fc1 + ReLU + BN1.
// 64 blocks x 256 thr; block computes Z into padded LDS (conflict-free),
// then its 4 waves produce h1 columns j=blk*4+wv (transposed [j][b]).
// Block 0 also writes the required Z output (row-major).
// ---------------------------------------------------------------------------
__global__ __launch_bounds__(256) void k_fc1z(
    const float* __restrict__ WX,   const float* __restrict__ co_w,
    const float* __restrict__ bn0g, const float* __restrict__ bn0b,
    const float* __restrict__ W1,   const float* __restrict__ b1,
    const float* __restrict__ bn1g, const float* __restrict__ bn1b,
    float* __restrict__ Zout, float* __restrict__ h1t)
{
    __shared__ float Zl[NP * 65];    // pad 65: conflict-free write & read
    const int tid  = threadIdx.x;
    const int wv   = tid >> 6;
    const int lane = tid & 63;       // == batch in fc1 stage
    const int blk  = blockIdx.x;

    if (tid < NP) {
        const int p = tid;
        float sum = 0.f, sq = 0.f;
        #pragma unroll 8
        for (int b = 0; b < BB; ++b) {
            const float r = fmaxf(WX[b * NP + p], 0.f);
            sum += r; sq += r * r;
        }
        const float m   = sum * (1.f / BB);
        const float var = sq * (1.f / BB) - m * m;
        const float sc  = rsqrtf(var + EPSV) * bn0g[p];
        const float bt  = bn0b[p];
        const float sig = 1.f / (1.f + expf(-co_w[p]));
        #pragma unroll 8
        for (int b = 0; b < BB; ++b) {
            const float r = fmaxf(WX[b * NP + p], 0.f);
            const float z = ((r - m) * sc + bt) * sig;
            Zl[p * 65 + b] = z;
            if (blk == 0) Zout[b * NP + p] = z;
        }
    }
    __syncthreads();

    const int j = blk * 4 + wv;      // 0..255
    float acc = b1[j];
    #pragma unroll 8
    for (int k = 0; k < NP; ++k)
        acc = fmaf(Zl[k * 65 + lane], W1[k * NH1 + j], acc);
    h1t[j * BB + lane] = bn_shfl(fmaxf(acc, 0.f), bn1g[j], bn1b[j]);
}

// ---------------------------------------------------------------------------
// fc2 + ReLU + BN2 from TRANSPOSED input [K][BB]. One block per column j.
// ---------------------------------------------------------------------------
template <int K, int NOUT>
__global__ void k_fc_bn_t(const float* __restrict__ in_t,  // [K][BB]
                          const float* __restrict__ W,     // [K, NOUT]
                          const float* __restrict__ bias,
                          const float* __restrict__ g,
                          const float* __restrict__ beta,
                          float* __restrict__ out_t)       // [NOUT][BB]
{
    const int j = blockIdx.x;
    const int b = threadIdx.x;  // 0..63
    float acc = bias[j];
    #pragma unroll 8
    for (int k = 0; k < K; ++k)
        acc = fmaf(in_t[k * BB + b], W[k * NOUT + j], acc);
    out_t[j * BB + b] = bn_shfl(fmaxf(acc, 0.f), g[j], beta[j]);
}

// ---------------------------------------------------------------------------
// Final Linear + row softmax from transposed h2 [NH2][BB].
// ---------------------------------------------------------------------------
__global__ void k_head(const float* __restrict__ h2t,  // [NH2][BB]
                       const float* __restrict__ Wo,   // [NH2, NC]
                       const float* __restrict__ bo,
                       float* __restrict__ y)          // [BB, NC]
{
    const int b = blockIdx.x;
    const int c = threadIdx.x;  // 0..31
    float acc = bo[c];
    #pragma unroll 8
    for (int k = 0; k < NH2; ++k)
        acc = fmaf(h2t[k * BB + b], Wo[k * NC + c], acc);
    float mx = acc;
    #pragma unroll
    for (int off = 16; off > 0; off >>= 1)
        mx = fmaxf(mx, __shfl_xor(mx, off));
    const float e = expf(acc - mx);
    float s = e;
    #pragma unroll
    for (int off = 16; off > 0; off >>= 1)
        s += __shfl_xor(s, off);
    y[b * NC + c] = e / s;
}

// ---------------------------------------------------------------------------
extern "C" void kernel_launch(void* const* d_in, const int* in_sizes, int n_in,
                              void* d_out, int out_size, void* d_ws, size_t ws_size,
                              hipStream_t stream)
{
    const float* x    = (const float*)d_in[0];
    const float* w    = (const float*)d_in[1];
    const float* co_w = (const float*)d_in[2];
    const float* bn0g = (const float*)d_in[3];
    const float* bn0b = (const float*)d_in[4];
    const float* W1   = (const float*)d_in[5];
    const float* b1   = (const float*)d_in[6];
    const float* bn1g = (const float*)d_in[7];
    const float* bn1b = (const float*)d_in[8];
    const float* W2   = (const float*)d_in[9];
    const float* b2   = (const float*)d_in[10];
    const float* bn2g = (const float*)d_in[11];
    const float* bn2b = (const float*)d_in[12];
    const float* Wo   = (const float*)d_in[13];
    const float* bo   = (const float*)d_in[14];
    const int*   idx  = (const int*)d_in[15];

    float* out = (float*)d_out;
    float* y   = out;               // [64, 32]  (output 0)
    float* Z   = out + BB * NC;     // [64, 128] (output 1)

    float* WX  = (float*)d_ws;          // 8192 f32
    float* h1t = WX + BB * NP;          // 16384 f32  [j][b]
    float* h2t = h1t + BB * NH1;        // 8192 f32   [j][b]

    k_zero<<<32, 256, 0, stream>>>(WX);
    k_scatter<<<CHUNKS * 2, 256, 0, stream>>>(x, w, idx, WX);
    k_fc1z<<<64, 256, 0, stream>>>(WX, co_w, bn0g, bn0b,
                                   W1, b1, bn1g, bn1b, Z, h1t);
    k_fc_bn_t<NH1, NH2><<<NH2, BB, 0, stream>>>(h1t, W2, b2, bn2g, bn2b, h2t);
    k_head<<<BB, NC, 0, stream>>>(h2t, Wo, bo, y);
}